// Round 9
// baseline (112.028 us; speedup 1.0000x reference)
//
#include <hip/hip_runtime.h>

#define NBINS 229
#define OUTF  88
#define MODEL 128
#define WSZ   30
#define WIN   61
#define TLEN  1024
#define BT    4096

#define NC1 648      // gemm1 real cols
#define NP1 704      // gemm1 padded cols (11*64)
#define NC2 216      // combine-gemm real cols

typedef short bf16x8 __attribute__((ext_vector_type(8)));
typedef float f32x4 __attribute__((ext_vector_type(4)));
typedef float f32x2 __attribute__((ext_vector_type(2)));
typedef unsigned short ushort_t;

__device__ __forceinline__ float sigmoid_f(float x) {
    return __builtin_amdgcn_rcpf(1.f + __expf(-x));
}
__device__ __forceinline__ ushort_t f2bf(float f) {
    unsigned u = __float_as_uint(f);
    return (ushort_t)((u + 0x7fffu + ((u >> 16) & 1u)) >> 16);
}

// 8-term tanh-trick partial: acc += v[d]*rcp(EH[d]*EP[d]+1).
// float2 form with PLAIN OPERATORS (default -ffp-contract=fast contracts
// a*b+c to fma; compiler MAY pack to v_pk_fma_f32 — no hand asm, the
// round-5/6 NaN source (hand VOP3P asm) must NOT be reintroduced).
__device__ __forceinline__ f32x2 dot8v(uint4 pv, float4 ha, float4 hb,
                                       float4 va, float4 vb, f32x2 acc) {
    const f32x2 one = {1.f, 1.f};
    f32x2 p, x, r;
    p = (f32x2){__uint_as_float(pv.x << 16), __uint_as_float(pv.x & 0xffff0000u)};
    x = (f32x2){ha.x, ha.y} * p + one;
    r = (f32x2){__builtin_amdgcn_rcpf(x.x), __builtin_amdgcn_rcpf(x.y)};
    acc = (f32x2){va.x, va.y} * r + acc;
    p = (f32x2){__uint_as_float(pv.y << 16), __uint_as_float(pv.y & 0xffff0000u)};
    x = (f32x2){ha.z, ha.w} * p + one;
    r = (f32x2){__builtin_amdgcn_rcpf(x.x), __builtin_amdgcn_rcpf(x.y)};
    acc = (f32x2){va.z, va.w} * r + acc;
    p = (f32x2){__uint_as_float(pv.z << 16), __uint_as_float(pv.z & 0xffff0000u)};
    x = (f32x2){hb.x, hb.y} * p + one;
    r = (f32x2){__builtin_amdgcn_rcpf(x.x), __builtin_amdgcn_rcpf(x.y)};
    acc = (f32x2){vb.x, vb.y} * r + acc;
    p = (f32x2){__uint_as_float(pv.w << 16), __uint_as_float(pv.w & 0xffff0000u)};
    x = (f32x2){hb.z, hb.w} * p + one;
    r = (f32x2){__builtin_amdgcn_rcpf(x.x), __builtin_amdgcn_rcpf(x.y)};
    acc = (f32x2){vb.z, vb.w} * r + acc;
    return acc;
}

__device__ __forceinline__ bf16x8 cvt8(f32x4 a, f32x4 b) {
    bf16x8 r;
    r[0] = (short)f2bf(a.x); r[1] = (short)f2bf(a.y);
    r[2] = (short)f2bf(a.z); r[3] = (short)f2bf(a.w);
    r[4] = (short)f2bf(b.x); r[5] = (short)f2bf(b.y);
    r[6] = (short)f2bf(b.z); r[7] = (short)f2bf(b.w);
    return r;
}
// spec rows are only 4B-aligned (229 floats) -> memcpy keeps align-4 loads
__device__ __forceinline__ bf16x8 loadA(const float* sp, int k0) {
    if (k0 > 228) return (bf16x8)(short)0;          // it=7, qd>=1: all pad
    f32x4 a, b;
    __builtin_memcpy(&a, sp + k0, 16);
    if (k0 <= 216) {
        __builtin_memcpy(&b, sp + k0 + 4, 16);
    } else {                                        // k0==224: valid 224..228
        b = (f32x4){sp[228], 0.f, 0.f, 0.f};
    }
    return cvt8(a, b);
}

// ---------------------------------------------------------------------------
// gemm_prep: MFMA bf16 GEMM1 + residual prep work, ONE kernel (unchanged from
// round 4 — verified). See round-4 comments for layout details.
// ---------------------------------------------------------------------------
#define GP_BLOCKS 897

__global__ __launch_bounds__(256) void gemm_prep(
    const float* __restrict__ spec,
    const float* __restrict__ Wf,  const float* __restrict__ bfr,
    const float* __restrict__ Wao, const float* __restrict__ bao,
    const float* __restrict__ Wl1,
    const float* __restrict__ Wac, const float* __restrict__ bac,
    const float* __restrict__ Wlc,
    const float* __restrict__ vo,  const float* __restrict__ vc,
    float* __restrict__ feat, float* __restrict__ EHo_,
    ushort_t* __restrict__ EPo_, ushort_t* __restrict__ EPc_,
    ushort_t* __restrict__ Rb_,  ushort_t* __restrict__ Qb_,
    ushort_t* __restrict__ B2b, float* __restrict__ bias2,
    float* __restrict__ sv)
{
    __shared__ ushort_t B1t[64 * 256];   // 32 KiB, chunk-XOR swizzled
    __shared__ float red[4];
    const int tid = threadIdx.x;
    const int b = blockIdx.x;

    if (b < 704) {
        const int e = b & 7, kf = b >> 3;
        const int rb = (e * 8 + (kf & 7)) * 64;
        const int cb = (kf >> 3) * 64;

        // ---- stage B tile: thread = (col n, k-quarter kq) ----
        {
            const int n  = tid & 63;
            const int kq = tid >> 6;            // 0..3
            const int ng = cb + n;
            const float* srcp = nullptr; int sstr = 0;
            if (ng < 88)       { srcp = Wf  + ng;                          sstr = 88;  }
            else if (ng < 216) { srcp = Wao + (ng - 88);                   sstr = 128; }
            else if (ng < 344) { srcp = Wao + (size_t)NBINS * 128 + (ng - 216); sstr = 128; }
            else if (ng < 472) { srcp = Wac + (size_t)176 * 128 + (ng - 344);   sstr = 128; }
            else if (ng < 560) { srcp = Wl1 + (ng - 472);                  sstr = 88;  }
            else if (ng < NC1) { srcp = Wlc + (size_t)176 * 88 + (ng - 560);    sstr = 88; }
            const int n31 = n & 31;
#pragma unroll
            for (int it = 0; it < 8; it++) {
                const int k8 = kq * 8 + it * 32;
                bf16x8 vv;
#pragma unroll
                for (int j = 0; j < 8; j++) {
                    const int k = k8 + j;
                    float v = (srcp && k < NBINS) ? srcp[(size_t)k * sstr] : 0.f;
                    vv[j] = (short)f2bf(v);
                }
                const int chunk = (kq + 4 * it) ^ n31;
                *(bf16x8*)&B1t[n * 256 + chunk * 8] = vv;
            }
        }
        __syncthreads();

        // ---- K loop ----
        const int wv = tid >> 6, ln = tid & 63;
        const int l15 = ln & 15, qd = ln >> 4;
        const float* sp = spec + (size_t)(rb + wv * 16 + l15) * NBINS;

        f32x4 acc[4];
#pragma unroll
        for (int nt = 0; nt < 4; nt++) acc[nt] = (f32x4){0.f, 0.f, 0.f, 0.f};

        bf16x8 af = loadA(sp, qd * 8);
#pragma unroll
        for (int it = 0; it < 8; it++) {
            const int nk = (it + 1 < 8) ? (it + 1) * 32 : 0;
            bf16x8 an = loadA(sp, nk + qd * 8);
            const int cq = qd + 4 * it;
#pragma unroll
            for (int nt = 0; nt < 4; nt++) {
                const int nn = nt * 16 + l15;
                bf16x8 bv = *(const bf16x8*)&B1t[nn * 256 + ((cq ^ (nn & 31)) << 3)];
                acc[nt] = __builtin_amdgcn_mfma_f32_16x16x32_bf16(
                    af, bv, acc[nt], 0, 0, 0);
            }
            af = an;
        }

        // ---- epilogue ----
        const int mbase = rb + wv * 16 + qd * 4;
#pragma unroll
        for (int nt = 0; nt < 4; nt++) {
            const int n = cb + nt * 16 + l15;
            if (n < NC1) {
                const float bn = (n < 88) ? bfr[n] : (n < 216 ? bao[n - 88] : 0.f);
#pragma unroll
                for (int r = 0; r < 4; r++) {
                    const int m = mbase + r;
                    float val = acc[nt][r] + bn;
                    if (n < 88) {
                        feat[(size_t)m * 88 + n] = val;
                    } else if (n < 216) {
                        EHo_[(size_t)m * 128 + (n - 88)] = __expf(val + val);
                    } else if (n < 344) {
                        EPo_[(size_t)m * 128 + (n - 216)] = f2bf(__expf(val + val));
                    } else if (n < 472) {
                        EPc_[(size_t)m * 128 + (n - 344)] = f2bf(__expf(val + val));
                    } else if (n < 560) {
                        Rb_[(size_t)m * 96 + (n - 472)] = f2bf(val);
                    } else {
                        Qb_[(size_t)m * 96 + (n - 560)] = f2bf(val);
                    }
                }
            }
        }
    } else if (b < 896) {                           // B2b
        int idx = (b - 704) * 256 + tid;
        int n = idx / 192, k = idx - n * 192;
        float v = 0.f;
        if (k < 176 && n < NC2)
            v = (n < 128) ? Wac[k * MODEL + n] : Wlc[k * 88 + (n - 128)];
        B2b[idx] = f2bf(v);
    } else {                                        // bias2 + sv
        bias2[tid] = (tid < 128) ? bac[tid] : 0.f;
        int wid = tid >> 6, lane = tid & 63;
        const float* vp = (wid < 2) ? vo : vc;
        float val = vp[(wid & 1) * 64 + lane];
#pragma unroll
        for (int m = 32; m; m >>= 1) val += __shfl_xor(val, m, 64);
        if (lane == 0) red[wid] = val;
        __syncthreads();
        if (tid == 0) {
            sv[0] = red[0] + red[1];
            sv[1] = red[2] + red[3];
        }
    }
}

// ---------------------------------------------------------------------------
// Fused attention, QB=8 (8 waves, 512 thr), XCD-swizzled, LDS TIME-SHARED:
// Plo/Plc never live simultaneously (nor Rl/Ql), so ONE window buffer pair
// (Pbuf/Rbuf) serves both attention passes — Plc/Ql are RE-STAGED into the
// same buffers after Phase B. LDS 77.9 -> 47.1 KB => 3 blocks/CU (24 waves,
// 6/SIMD; was 2 blocks) -> cross-block overlap covers the low-width PV /
// staging / barrier tails. __launch_bounds__(512,6) caps VGPR at ~85.
//   A-dot : energies (float2 tanh trick), softmax (no max: |eng|<~15),
//           a_onset out + bf16 weights into Am band matrix
//   PV-A  : MFMA [16x96 Am]@[96x96 Rbuf] -> sigmoid -> onset_pred + Xb
//   B     : C2 = Xb @ B2 (MFMA) -> EHc / basec
//   restage: Pbuf <- EPc windows, Rbuf <- Qb windows
//   C-dot : energies with Pbuf/EHc -> a_frame + Am
//   PV-C  : MFMA Am@Rbuf + basec -> sigmoid -> frame_pred
// K=96 MFMA overrun contract (every overrun byte initialized+finite; A=0
// does NOT mask NaN B): PV reads Rbuf rows 68..95 -> lands in Xb (fully
// written, finite). Pbuf pad cols 128..135 are NEVER read now (dot reads
// chunks 0..15 only) — no pad zeroing needed. Am zeroed rows 0..15; C-dot
// band overwrites exactly A-dot's band cells.
// ---------------------------------------------------------------------------
#define ROWS 68
#define EPST 136
#define RST  96
#define XST  200
#define AST  104

#define PB_O  0                        // 68*136 u16 = 18496 B
#define RB_O  (ROWS * EPST)            // u16 9248
#define XB_O  (RB_O + ROWS * RST)      // u16 15776: 16*200
#define AM_O  (XB_O + 16 * XST)        // u16 18976: 16*104
#define EHC_O (AM_O + 16 * AST)        // u16 20640: 8*128 f32
#define BSC_O (EHC_O + 2 * 8 * 128)    // u16 22688: 8*88 f32
#define SH_U16 (BSC_O + 2 * 8 * 88)    // 24096 u16 = 48192 B

__global__ __launch_bounds__(512, 6) void attn_fused(
    const float* __restrict__ EHo,
    const ushort_t* __restrict__ EPo_g,
    const ushort_t* __restrict__ Rb,
    const ushort_t* __restrict__ EPc_g,
    const ushort_t* __restrict__ Qb,
    const float* __restrict__ feat,          // [BT,88] fp32 (= out4)
    const ushort_t* __restrict__ B2b,        // [256,192] bf16 n-major
    const float* __restrict__ bias2,
    const float* __restrict__ vo, const float* __restrict__ vc,
    const float* __restrict__ svp,
    const float* __restrict__ bl1, const float* __restrict__ blc,
    float* __restrict__ a_o_out, float* __restrict__ onset_out,
    float* __restrict__ a_c_out, float* __restrict__ frame_out)
{
    __shared__ alignas(16) ushort_t SH[SH_U16];
    ushort_t* Pbuf = SH + PB_O;
    ushort_t* Rbuf = SH + RB_O;
    ushort_t* Xb   = SH + XB_O;
    ushort_t* Am   = SH + AM_O;
    float*    EHc   = (float*)(SH + EHC_O);
    float*    basec = (float*)(SH + BSC_O);

    const int tid = threadIdx.x;
    const int s0 = ((blockIdx.x & 7) * 64 + (blockIdx.x >> 3)) * 8;
    const int t0 = s0 & (TLEN - 1);

    // ---- prologue staging ----
    // Pbuf <- EPo windows (68 x 128 bf16, chunk-XOR swizzled); pad rows = 1.0
    for (int i = tid; i < ROWS * 16; i += 512) {
        int j = i >> 4, c = (i & 15) * 8;
        int cs = ((i & 15) ^ ((j >> 3) & 7)) * 8;
        int tg = t0 + j - WSZ;
        uint4 vP = {0x3f803f80u, 0x3f803f80u, 0x3f803f80u, 0x3f803f80u};
        if ((unsigned)tg < (unsigned)TLEN)
            vP = *(const uint4*)&EPo_g[(size_t)(s0 - WSZ + j) * 128 + c];
        *(uint4*)&Pbuf[j * EPST + cs] = vP;
    }
    // Rbuf <- R windows (68 x 96 bf16); pad rows = 0
    for (int i = tid; i < ROWS * 12; i += 512) {
        int j = i / 12, c = (i - j * 12) * 8;
        int tg = t0 + j - WSZ;
        uint4 vR = {0u, 0u, 0u, 0u};
        if ((unsigned)tg < (unsigned)TLEN)
            vR = *(const uint4*)&Rb[(size_t)(s0 - WSZ + j) * 96 + c];
        *(uint4*)&Rbuf[j * RST + c] = vR;
    }
    // Xb rows 0..7 cols 0..87 = feat bf16; rest zero (rows 8..15 pad; also
    // serves as the finite landing zone for the PV K=96 overrun)
    for (int i = tid; i < 16 * XST; i += 512) {
        int r = i / XST, k = i - r * XST;
        ushort_t v = 0;
        if (r < 8 && k < 88) v = f2bf(feat[(size_t)(s0 + r) * 88 + k]);
        Xb[i] = v;
    }
    // Am zero: ALL 16 rows, cols 0..95
    {
        unsigned* am32 = (unsigned*)Am;
        for (int i = tid; i < 16 * 48; i += 512)
            am32[(i / 48) * 52 + (i % 48)] = 0u;
    }
    __syncthreads();

    const int q = tid >> 6;
    const int w = tid & 63;
    const int s = s0 + q;
    const int su = __builtin_amdgcn_readfirstlane(s);
    const int row = q + ((w < WIN) ? w : 0);
    const int rsw = (row >> 3) & 7;
    const int l15 = w & 15, qd = w >> 4;

    // ---- Phase A-dot: onset energies + softmax + Am ----
    {
        const ushort_t* pb = &Pbuf[row * EPST];
        const float* hrow = EHo + (size_t)su * 128;   // uniform -> s_load
        f32x2 acc2 = {0.f, 0.f};
#pragma unroll
        for (int d8 = 0; d8 < 16; d8++) {
            uint4 pv = *(const uint4*)(pb + ((d8 ^ rsw) << 3));
            float4 ha = *(const float4*)(hrow + d8 * 8);
            float4 hb = *(const float4*)(hrow + d8 * 8 + 4);
            float4 va = *(const float4*)(vo + d8 * 8);
            float4 vb = *(const float4*)(vo + d8 * 8 + 4);
            acc2 = dot8v(pv, ha, hb, va, vb, acc2);
        }
        float eng = svp[0] - 2.f * (acc2.x + acc2.y);
        float ex = (w < WIN) ? __expf(eng) : 0.f;
        float sm = ex;
#pragma unroll
        for (int m = 32; m; m >>= 1) sm += __shfl_xor(sm, m, 64);
        float a = ex * __builtin_amdgcn_rcpf(sm);
        if (w < WIN) {
            a_o_out[(size_t)s * WIN + w] = a;
            Am[q * AST + q + w] = f2bf(a);
        }
    }
    __syncthreads();

    // ---- PV-A: MFMA Am @ Rbuf -> onset_pred + Xb ----
    if (q < 6) {
        f32x4 acc = (f32x4){0.f, 0.f, 0.f, 0.f};
#pragma unroll
        for (int kk = 0; kk < 3; kk++) {
            bf16x8 av = *(const bf16x8*)&Am[l15 * AST + kk * 32 + qd * 8];
            bf16x8 bv;
#pragma unroll
            for (int j = 0; j < 8; j++)
                bv[j] = (short)Rbuf[(kk * 32 + qd * 8 + j) * RST + q * 16 + l15];
            acc = __builtin_amdgcn_mfma_f32_16x16x32_bf16(av, bv, acc, 0, 0, 0);
        }
        const int f = q * 16 + l15;
        if (qd < 2 && f < 88) {
            const float bb = bl1[f];
#pragma unroll
            for (int r = 0; r < 4; r++) {
                const int m = qd * 4 + r;
                float p = sigmoid_f(acc[r] + bb);
                onset_out[(size_t)(s0 + m) * OUTF + f] = p;
                Xb[m * XST + 88 + f] = f2bf(p);
            }
        }
    }
    __syncthreads();

    // ---- Phase B: C2 = Xb @ B2 via MFMA; 14 n-tiles over 8 waves ----
    {
#pragma unroll
        for (int rt = 0; rt < 2; rt++) {
            const int t = q + rt * 8;
            if (t < 14) {
                const int n0 = t * 16;
                const ushort_t* bp = B2b + (size_t)(n0 + l15) * 192 + qd * 8;
                const ushort_t* ap = &Xb[l15 * XST + qd * 8];
                f32x4 acc = (f32x4){0.f, 0.f, 0.f, 0.f};
#pragma unroll
                for (int it = 0; it < 6; it++) {
                    bf16x8 av = *(const bf16x8*)(ap + it * 32);
                    bf16x8 bv = *(const bf16x8*)(bp + it * 32);
                    acc = __builtin_amdgcn_mfma_f32_16x16x32_bf16(
                        av, bv, acc, 0, 0, 0);
                }
                if (qd < 2) {
                    const int n = n0 + l15;
                    const float b2 = bias2[n];
#pragma unroll
                    for (int r = 0; r < 4; r++) {
                        const int m = qd * 4 + r;
                        float val = acc[r] + b2;
                        if (n < 128)        EHc[m * 128 + n] = __expf(val + val);
                        else if (n < NC2)   basec[m * 88 + (n - 128)] = val;
                    }
                }
            }
        }
    }
    __syncthreads();

    // ---- re-stage: Pbuf <- EPc windows, Rbuf <- Q windows ----
    for (int i = tid; i < ROWS * 16; i += 512) {
        int j = i >> 4, c = (i & 15) * 8;
        int cs = ((i & 15) ^ ((j >> 3) & 7)) * 8;
        int tg = t0 + j - WSZ;
        uint4 vC = {0x3f803f80u, 0x3f803f80u, 0x3f803f80u, 0x3f803f80u};
        if ((unsigned)tg < (unsigned)TLEN)
            vC = *(const uint4*)&EPc_g[(size_t)(s0 - WSZ + j) * 128 + c];
        *(uint4*)&Pbuf[j * EPST + cs] = vC;
    }
    for (int i = tid; i < ROWS * 12; i += 512) {
        int j = i / 12, c = (i - j * 12) * 8;
        int tg = t0 + j - WSZ;
        uint4 vQ = {0u, 0u, 0u, 0u};
        if ((unsigned)tg < (unsigned)TLEN)
            vQ = *(const uint4*)&Qb[(size_t)(s0 - WSZ + j) * 96 + c];
        *(uint4*)&Rbuf[j * RST + c] = vQ;
    }
    __syncthreads();

    // ---- Phase C-dot: frame energies + softmax + Am ----
    {
        const ushort_t* pb = &Pbuf[row * EPST];
        const float* hl = &EHc[q * 128];
        f32x2 acc2 = {0.f, 0.f};
#pragma unroll
        for (int d8 = 0; d8 < 16; d8++) {
            uint4 pv = *(const uint4*)(pb + ((d8 ^ rsw) << 3));
            float4 ha = *(const float4*)(hl + d8 * 8);
            float4 hb = *(const float4*)(hl + d8 * 8 + 4);
            float4 va = *(const float4*)(vc + d8 * 8);
            float4 vb = *(const float4*)(vc + d8 * 8 + 4);
            acc2 = dot8v(pv, ha, hb, va, vb, acc2);
        }
        float eng = svp[1] - 2.f * (acc2.x + acc2.y);
        float ex = (w < WIN) ? __expf(eng) : 0.f;
        float sm = ex;
#pragma unroll
        for (int m = 32; m; m >>= 1) sm += __shfl_xor(sm, m, 64);
        float a = ex * __builtin_amdgcn_rcpf(sm);
        if (w < WIN) {
            a_c_out[(size_t)s * WIN + w] = a;
            Am[q * AST + q + w] = f2bf(a);
        }
    }
    __syncthreads();

    // ---- PV-C: MFMA Am @ Rbuf(=Ql) + basec -> frame_pred ----
    if (q < 6) {
        f32x4 acc = (f32x4){0.f, 0.f, 0.f, 0.f};
#pragma unroll
        for (int kk = 0; kk < 3; kk++) {
            bf16x8 av = *(const bf16x8*)&Am[l15 * AST + kk * 32 + qd * 8];
            bf16x8 bv;
#pragma unroll
            for (int j = 0; j < 8; j++)
                bv[j] = (short)Rbuf[(kk * 32 + qd * 8 + j) * RST + q * 16 + l15];
            acc = __builtin_amdgcn_mfma_f32_16x16x32_bf16(av, bv, acc, 0, 0, 0);
        }
        const int f = q * 16 + l15;
        if (qd < 2 && f < 88) {
            const float bb = blc[f];
#pragma unroll
            for (int r = 0; r < 4; r++) {
                const int m = qd * 4 + r;
                float p = sigmoid_f(acc[r] + bb + basec[m * 88 + f]);
                frame_out[(size_t)(s0 + m) * OUTF + f] = p;
            }
        }
    }
}

// ---------------------------------------------------------------------------
extern "C" void kernel_launch(void* const* d_in, const int* in_sizes, int n_in,
                              void* d_out, int out_size, void* d_ws, size_t ws_size,
                              hipStream_t stream)
{
    const float* spec = (const float*)d_in[0];
    const float* Wf   = (const float*)d_in[1];
    const float* bf_  = (const float*)d_in[2];
    const float* Wao  = (const float*)d_in[3];
    const float* bao  = (const float*)d_in[4];
    const float* vo   = (const float*)d_in[5];
    const float* Wl1  = (const float*)d_in[6];
    const float* bl1  = (const float*)d_in[7];
    const float* Wac  = (const float*)d_in[8];
    const float* bac  = (const float*)d_in[9];
    const float* vc   = (const float*)d_in[10];
    const float* Wlc  = (const float*)d_in[11];
    const float* blc  = (const float*)d_in[12];

    float* out  = (float*)d_out;
    float* out0 = out;                 // frame_pred [BT,88]
    float* out1 = out + 360448;        // a_frame    [BT,61]
    float* out2 = out + 610304;        // onset_pred [BT,88]
    float* out3 = out + 970752;        // a_onset    [BT,61]
    float* out4 = out + 1220608;       // feat_pred  [BT,88]

    // Workspace layout (float offsets; u16 arrays occupy count/2 floats):
    //   sv @0 (16) | bias2 @16 (256) | B2b u16 @272 (24576f)
    //   EHo f32 @24848 (524288f) | EPo u16 @549136 (262144f)
    //   EPc u16 @811280 (262144f) | Rb u16 @1073424 (196608f)
    //   Qb u16 @1270032 (196608f) -> ends 1466640 (~5.9MB)
    float* ws = (float*)d_ws;
    float*    sv    = ws;
    float*    bias2 = ws + 16;
    ushort_t* B2b   = (ushort_t*)(ws + 272);
    float*    EHo   = ws + 24848;
    ushort_t* EPo   = (ushort_t*)(ws + 549136);
    ushort_t* EPc   = (ushort_t*)(ws + 811280);
    ushort_t* Rb    = (ushort_t*)(ws + 1073424);
    ushort_t* Qb    = (ushort_t*)(ws + 1270032);
    (void)ws_size; (void)in_sizes; (void)n_in; (void)out_size;

    gemm_prep<<<GP_BLOCKS, 256, 0, stream>>>(
        spec, Wf, bf_, Wao, bao, Wl1, Wac, bac, Wlc, vo, vc,
        out4, EHo, EPo, EPc, Rb, Qb, B2b, bias2, sv);

    attn_fused<<<BT / 8, 512, 0, stream>>>(
        EHo, EPo, Rb, EPc, Qb, out4, B2b, bias2, vo, vc, sv, bl1, blc,
        out3, out2, out1, out0);
}